// Round 3
// baseline (1672.305 us; speedup 1.0000x reference)
//
#include <hip/hip_runtime.h>
#include <math.h>

typedef unsigned short u16;
typedef __attribute__((ext_vector_type(8))) short bf16x8;
typedef __attribute__((ext_vector_type(4))) float f32x4;

#define LDSS 40   // 32 k-elems + 8 pad (bf16)
#define BK 32

__device__ __forceinline__ float bf2f(u16 u) {
    unsigned x = ((unsigned)u) << 16; float f; __builtin_memcpy(&f, &x, 4); return f;
}
__device__ __forceinline__ u16 f2bf(float f) {
    unsigned x; __builtin_memcpy(&x, &f, 4);
    unsigned lsb = (x >> 16) & 1u; x += 0x7fffu + lsb; return (u16)(x >> 16);
}

// ---------------- input dtype detector ----------------
// Samples even-index u16s of w_qkv. bf16 world: all decode to sane small values.
// f32 world: even u16s are low-mantissa bits -> ~55% insane as bf16. flag=1 => f32 inputs.
__global__ __launch_bounds__(256) void k_detect(const u16* __restrict__ wq, int* __restrict__ flag) {
    const int tid = threadIdx.x;
    int cnt = 0;
    for (int i = tid; i < 2048; i += 256) {
        float v = fabsf(bf2f(wq[2 * i]));
        if (!(v < 1e4f) || (v != 0.f && v < 1e-30f)) cnt++;   // !(v<1e4) also catches NaN
    }
    for (int off = 32; off; off >>= 1) cnt += __shfl_down(cnt, off, 64);
    __shared__ int red[4];
    int lane = tid & 63, w = tid >> 6;
    if (!lane) red[w] = cnt;
    __syncthreads();
    if (!tid) flag[0] = (red[0] + red[1] + red[2] + red[3] > 204) ? 1 : 0;
}

// ---------------- small-vector convert: [bqkv|bgate|bproj|lng|lnb] -> canonical bf16 ----------------
__global__ __launch_bounds__(256) void k_cvec(const void* __restrict__ bqkv, const void* __restrict__ bgate,
                                              const void* __restrict__ bproj, const void* __restrict__ lng,
                                              const void* __restrict__ lnb, const int* __restrict__ flag,
                                              u16* __restrict__ cv) {
    int i = blockIdx.x * 256 + threadIdx.x;   // 0..7167
    const void* src; int off;
    if (i < 3072)      { src = bqkv;  off = i; }
    else if (i < 4096) { src = bgate; off = i - 3072; }
    else if (i < 5120) { src = bproj; off = i - 4096; }
    else if (i < 6144) { src = lng;   off = i - 5120; }
    else               { src = lnb;   off = i - 6144; }
    cv[i] = flag[0] ? f2bf(((const float*)src)[off]) : ((const u16*)src)[off];
}

// ---------------- shared MFMA 128x128-tile K-loop ----------------
// A: row-major, rows ar0.., k-contig, stride as_. B: row-major, rows br0.., k-contig, stride bs_.
// acc[mi][ni] += A-tile * B-tile^T over ksteps*32 k.
__device__ __forceinline__ void gemm_loop(const u16* __restrict__ Ab, long ar0, long as_, long ka0,
                                          const u16* __restrict__ Bb, long br0, long bs_, long kb0,
                                          int ksteps, u16* As, u16* Bs, int tid, f32x4 acc[4][4]) {
    const int lane = tid & 63;
    const int waveM = (tid >> 7) & 1;
    const int waveN = (tid >> 6) & 1;
    const int quad = lane >> 4, l16 = lane & 15;
    for (int kt = 0; kt < ksteps; ++kt) {
        uint4 ra[2], rb[2];
        const long ka = ka0 + (long)kt * BK, kb = kb0 + (long)kt * BK;
#pragma unroll
        for (int i = 0; i < 2; ++i) {
            int ch = tid + i * 256; int rr = ch >> 2, cc = ch & 3;
            ra[i] = *(const uint4*)(Ab + (ar0 + rr) * as_ + ka + cc * 8);
            rb[i] = *(const uint4*)(Bb + (br0 + rr) * bs_ + kb + cc * 8);
        }
        __syncthreads();
#pragma unroll
        for (int i = 0; i < 2; ++i) {
            int ch = tid + i * 256; int rr = ch >> 2, cc = ch & 3;
            *(uint4*)(As + rr * LDSS + cc * 8) = ra[i];
            *(uint4*)(Bs + rr * LDSS + cc * 8) = rb[i];
        }
        __syncthreads();
        bf16x8 af[4], bv[4];
#pragma unroll
        for (int mi = 0; mi < 4; ++mi)
            af[mi] = *(const bf16x8*)(As + (waveM * 64 + mi * 16 + l16) * LDSS + quad * 8);
#pragma unroll
        for (int ni = 0; ni < 4; ++ni)
            bv[ni] = *(const bf16x8*)(Bs + (waveN * 64 + ni * 16 + l16) * LDSS + quad * 8);
#pragma unroll
        for (int mi = 0; mi < 4; ++mi)
#pragma unroll
            for (int ni = 0; ni < 4; ++ni)
                acc[mi][ni] = __builtin_amdgcn_mfma_f32_16x16x32_bf16(af[mi], bv[ni], acc[mi][ni], 0, 0, 0);
    }
}

#define EPI_COORDS \
    const int lane = tid & 63; const int quad = lane >> 4; const int l16 = lane & 15; \
    const int waveM = (tid >> 7) & 1; const int waveN = (tid >> 6) & 1;

#define ZERO_ACC(acc) \
    _Pragma("unroll") for (int mi = 0; mi < 4; ++mi) \
    _Pragma("unroll") for (int ni = 0; ni < 4; ++ni) acc[mi][ni] = (f32x4){0.f, 0.f, 0.f, 0.f};

// ---------------- weight transpose (dtype-aware read, bf16 write) ----------------
__global__ __launch_bounds__(256) void k_transw(const void* __restrict__ wqkv, const void* __restrict__ wgate,
                                                const void* __restrict__ wproj, const int* __restrict__ flag,
                                                u16* __restrict__ Wt, u16* __restrict__ WpT) {
    long idx = (long)blockIdx.x * 256 + threadIdx.x;   // 5120*1024
    int n = (int)(idx >> 10), k = (int)(idx & 1023);
    const void* src; long off;
    if (n < 3072)       { src = wqkv;  off = (long)k * 3072 + n; }
    else if (n < 4096)  { src = wgate; off = (long)k * 1024 + (n - 3072); }
    else                { src = wproj; off = (long)k * 1024 + (n - 4096); }
    u16 v = flag[0] ? f2bf(((const float*)src)[off]) : ((const u16*)src)[off];
    if (n < 4096) Wt[(long)n * 1024 + k] = v;
    else          WpT[(long)(n - 4096) * 1024 + k] = v;
}

// ---------------- LayerNorm (dtype-aware read of x) ----------------
__global__ __launch_bounds__(256) void k_ln(const void* __restrict__ xin, const u16* __restrict__ cv,
                                            const int* __restrict__ flag, u16* __restrict__ XN) {
    const long t = blockIdx.x; const int tid = threadIdx.x;
    const int fl = flag[0];
    float v[4], s = 0.f, sq = 0.f;
#pragma unroll
    for (int i = 0; i < 4; ++i) {
        long a = t * 1024 + tid + i * 256;
        v[i] = fl ? ((const float*)xin)[a] : bf2f(((const u16*)xin)[a]);
        s += v[i]; sq += v[i] * v[i];
    }
    for (int off = 32; off; off >>= 1) { s += __shfl_down(s, off, 64); sq += __shfl_down(sq, off, 64); }
    __shared__ float red[8];
    int lane = tid & 63, w = tid >> 6;
    if (!lane) { red[w] = s; red[4 + w] = sq; }
    __syncthreads();
    float S = red[0] + red[1] + red[2] + red[3];
    float SQ = red[4] + red[5] + red[6] + red[7];
    float mu = S * (1.f / 1024.f);
    float var = SQ * (1.f / 1024.f) - mu * mu;
    float rs = rsqrtf(var + 1e-5f);
#pragma unroll
    for (int i = 0; i < 4; ++i) {
        int col = tid + i * 256;
        XN[t * 1024 + col] = f2bf((v[i] - mu) * rs * bf2f(cv[5120 + col]) + bf2f(cv[6144 + col]));
    }
}

// ---------------- GEMM1: [q|k|v|gate] = XN @ Wt^T + bias ; q gets elu+1; v written transposed ----------------
__global__ __launch_bounds__(256) void k_gemm1(const u16* __restrict__ XN, const u16* __restrict__ Wt,
                                               const u16* __restrict__ cv,
                                               u16* __restrict__ Q, u16* __restrict__ K,
                                               u16* __restrict__ G, u16* __restrict__ vT) {
    __shared__ u16 As[128 * LDSS], Bs[128 * LDSS];
    const int tid = threadIdx.x, bid = blockIdx.x;
    const int nt = bid & 31, mt = bid >> 5;
    f32x4 acc[4][4]; ZERO_ACC(acc);
    gemm_loop(XN, (long)mt * 128, 1024, 0, Wt, (long)nt * 128, 1024, 0, 32, As, Bs, tid, acc);
    EPI_COORDS
    const int grp = nt >> 3;   // 0=q 1=k 2=v 3=gate (block-uniform)
#pragma unroll
    for (int mi = 0; mi < 4; ++mi)
#pragma unroll
        for (int ni = 0; ni < 4; ++ni) {
            int colg = nt * 128 + waveN * 64 + ni * 16 + l16;
            int d = colg & 1023;
            float bias = (grp < 3) ? bf2f(cv[colg]) : bf2f(cv[3072 + d]);
            int row0 = mt * 128 + waveM * 64 + mi * 16 + quad * 4;
            if (grp == 2) {
                int b = row0 >> 12; int tb = row0 & 4095;
                ushort4 pk;
                pk.x = f2bf(acc[mi][ni][0] + bias);
                pk.y = f2bf(acc[mi][ni][1] + bias);
                pk.z = f2bf(acc[mi][ni][2] + bias);
                pk.w = f2bf(acc[mi][ni][3] + bias);
                *(ushort4*)(vT + (long)b * 4194304 + (long)d * 4096 + tb) = pk;
            } else {
                u16* dst = (grp == 0) ? Q : (grp == 1) ? K : G;
#pragma unroll
                for (int r = 0; r < 4; ++r) {
                    float v = acc[mi][ni][r] + bias;
                    if (grp == 0) v = v > 0.f ? v + 1.f : expf(v);   // elu(q)+1 fused, f32
                    dst[(long)(row0 + r) * 1024 + d] = f2bf(v);
                }
            }
        }
}

// ---------------- k = elu(k_raw * sigmoid(gate)) + 1, in place ----------------
__global__ __launch_bounds__(256) void k_act(u16* __restrict__ K, const u16* __restrict__ G) {
    const long t = blockIdx.x; const int tid = threadIdx.x;
#pragma unroll
    for (int i = 0; i < 4; ++i) {
        long a = t * 1024 + tid + i * 256;
        float kk = bf2f(K[a]) / (1.f + expf(-bf2f(G[a])));
        kk = kk > 0.f ? kk + 1.f : expf(kk);
        K[a] = f2bf(kk);
    }
}

// ---------------- tiled transpose: kT[b][d][t] <- K[t][d] ----------------
__global__ __launch_bounds__(256) void k_transk(const u16* __restrict__ K, u16* __restrict__ kT) {
    const int bid = blockIdx.x, tid = threadIdx.x;   // 256 tt x 16 dt
    const int dt = bid & 15, tt = bid >> 4;
    __shared__ u16 tileS[64][65];
#pragma unroll
    for (int i = 0; i < 16; ++i) {
        int idx = tid + i * 256; int r = idx >> 6, cc = idx & 63;
        tileS[r][cc] = K[(long)(tt * 64 + r) * 1024 + dt * 64 + cc];
    }
    __syncthreads();
    long tg = (long)tt * 64; int b = (int)(tg >> 12); long tb = tg & 4095;
#pragma unroll
    for (int i = 0; i < 16; ++i) {
        int idx = tid + i * 256; int r = idx >> 6, cc = idx & 63;
        kT[(long)b * 4194304 + (long)(dt * 64 + r) * 4096 + tb + cc] = tileS[cc][r];
    }
}

// ---------------- per-chunk k sums: csum[b][c][d] ----------------
__global__ __launch_bounds__(256) void k_csum(const u16* __restrict__ K, float* __restrict__ csum) {
    const int bid = blockIdx.x, tid = threadIdx.x;   // 64 blocks: b(2) c(2) dg(2)
    const int b = bid >> 4, c = (bid >> 2) & 3, dg = bid & 3;
    const int d = dg * 256 + tid;
    const u16* base = K + ((long)b * 4096 + c * 1024) * 1024 + d;
    float s = 0.f;
    for (int t = 0; t < 1024; ++t) s += bf2f(base[(long)t * 1024]);
    csum[((b * 4 + c) << 10) + d] = s;
}

// ---------------- pass1: ST[b][c][d][e] = sum_s v[s,d] k[s,e] ----------------
__global__ __launch_bounds__(256) void k_pass1(const u16* __restrict__ kT, const u16* __restrict__ vT,
                                               u16* __restrict__ ST) {
    __shared__ u16 As[128 * LDSS], Bs[128 * LDSS];
    const int tid = threadIdx.x, bid = blockIdx.x;
    const int tile = bid & 63, c = (bid >> 6) & 3, b = bid >> 8;
    const int dt = tile >> 3, et = tile & 7;
    f32x4 acc[4][4]; ZERO_ACC(acc);
    gemm_loop(vT + (long)b * 4194304, (long)dt * 128, 4096, (long)c * 1024,
              kT + (long)b * 4194304, (long)et * 128, 4096, (long)c * 1024, 32, As, Bs, tid, acc);
    EPI_COORDS
    u16* dst = ST + ((long)(b * 4 + c) << 20);
#pragma unroll
    for (int mi = 0; mi < 4; ++mi)
#pragma unroll
        for (int ni = 0; ni < 4; ++ni)
#pragma unroll
            for (int r = 0; r < 4; ++r) {
                long d = dt * 128 + waveM * 64 + mi * 16 + quad * 4 + r;
                long e = et * 128 + waveN * 64 + ni * 16 + l16;
                dst[d * 1024 + e] = f2bf(acc[mi][ni][r]);
            }
}

// ---------------- in-place exclusive prefix over chunk states ----------------
__global__ __launch_bounds__(256) void k_stpre(u16* __restrict__ ST) {
    const long gid = (long)blockIdx.x * 256 + threadIdx.x;  // 4M
    const int b = (int)(gid >> 20); const long rem = gid & 0xFFFFF;
    float run = 0.f;
    for (int c = 0; c < 4; ++c) {
        long a = (((long)(b * 4 + c)) << 20) + rem;
        float v = bf2f(ST[a]);
        ST[a] = f2bf(run);
        run += v;
    }
}

// ---------------- pass2a: P[t, s_local] = masked q_t . k_s (intra chunk) ----------------
__global__ __launch_bounds__(256) void k_pass2a(const u16* __restrict__ Q, const u16* __restrict__ K,
                                                u16* __restrict__ P) {
    const int tid = threadIdx.x, bid = blockIdx.x;
    const int tile = bid & 63, c = (bid >> 6) & 3, b = bid >> 8;
    const int ti = tile >> 3, si = tile & 7;
    const long trow0 = (long)b * 4096 + c * 1024 + ti * 128;
    if (si > ti) {  // strictly-upper tile: zeros (block-uniform)
#pragma unroll
        for (int i = 0; i < 64; ++i) {
            int idx = tid + i * 256; int rr = idx >> 7, cc = idx & 127;
            P[(trow0 + rr) * 1024 + si * 128 + cc] = 0;
        }
        return;
    }
    __shared__ u16 As[128 * LDSS], Bs[128 * LDSS];
    const long srow0 = (long)b * 4096 + c * 1024 + si * 128;
    f32x4 acc[4][4]; ZERO_ACC(acc);
    gemm_loop(Q, trow0, 1024, 0, K, srow0, 1024, 0, 32, As, Bs, tid, acc);
    EPI_COORDS
#pragma unroll
    for (int mi = 0; mi < 4; ++mi)
#pragma unroll
        for (int ni = 0; ni < 4; ++ni) {
            int slc = si * 128 + waveN * 64 + ni * 16 + l16;
#pragma unroll
            for (int r = 0; r < 4; ++r) {
                int tl = waveM * 64 + mi * 16 + quad * 4 + r;
                float v = (ti * 128 + tl >= slc) ? acc[mi][ni][r] : 0.f;
                P[(trow0 + tl) * 1024 + slc] = f2bf(v);
            }
        }
}

// ---------------- den[t] = q_t . chunk_prefix + rowsum(P) + eps ----------------
__global__ __launch_bounds__(256) void k_den(const u16* __restrict__ Q, const u16* __restrict__ P,
                                             const float* __restrict__ csum, float* __restrict__ den) {
    const long t = blockIdx.x; const int tid = threadIdx.x;
    const int b = (int)(t >> 12), c = (int)((t >> 10) & 3);
    float s = 0.f;
#pragma unroll
    for (int i = 0; i < 4; ++i) {
        int e = tid + i * 256;
        float kp = 0.f;
        for (int cp = 0; cp < c; ++cp) kp += csum[((b * 4 + cp) << 10) + e];
        s += bf2f(Q[t * 1024 + e]) * kp + bf2f(P[t * 1024 + e]);
    }
    for (int off = 32; off; off >>= 1) s += __shfl_down(s, off, 64);
    __shared__ float red[4];
    int lane = tid & 63, w = tid >> 6;
    if (!lane) red[w] = s;
    __syncthreads();
    if (!tid) den[t] = red[0] + red[1] + red[2] + red[3] + 1e-6f;
}

// ---------------- pass2b: y[t,d] = (q@ST_prefix + P@V)/den ----------------
__global__ __launch_bounds__(256) void k_pass2b(const u16* __restrict__ Q, const u16* __restrict__ ST,
                                                const u16* __restrict__ P, const u16* __restrict__ vT,
                                                const float* __restrict__ den, u16* __restrict__ Yb) {
    __shared__ u16 As[128 * LDSS], Bs[128 * LDSS];
    const int tid = threadIdx.x, bid = blockIdx.x;
    const int tile = bid & 63, c = (bid >> 6) & 3, b = bid >> 8;
    const int ti = tile >> 3, di = tile & 7;
    const long trow0 = (long)b * 4096 + c * 1024 + ti * 128;
    f32x4 acc[4][4]; ZERO_ACC(acc);
    if (c > 0)  // inter-chunk (prefix is zero for c==0)
        gemm_loop(Q, trow0, 1024, 0, ST + ((long)(b * 4 + c) << 20), (long)di * 128, 1024, 0,
                  32, As, Bs, tid, acc);
    // intra-chunk: only s-tiles <= ti carry mass (P upper region zeroed)
    gemm_loop(P, trow0, 1024, 0, vT + (long)b * 4194304, (long)di * 128, 4096, (long)c * 1024,
              (ti + 1) * 4, As, Bs, tid, acc);
    EPI_COORDS
#pragma unroll
    for (int mi = 0; mi < 4; ++mi)
#pragma unroll
        for (int ni = 0; ni < 4; ++ni) {
            long d = di * 128 + waveN * 64 + ni * 16 + l16;
#pragma unroll
            for (int r = 0; r < 4; ++r) {
                long t = trow0 + waveM * 64 + mi * 16 + quad * 4 + r;
                Yb[t * 1024 + d] = f2bf(acc[mi][ni][r] / den[t]);
            }
        }
}

// ---------------- proj: out = y @ w_proj + b_proj (dtype-aware store) ----------------
__global__ __launch_bounds__(256) void k_proj(const u16* __restrict__ Yb, const u16* __restrict__ WpT,
                                              const u16* __restrict__ cv, const int* __restrict__ flag,
                                              void* __restrict__ out) {
    __shared__ u16 As[128 * LDSS], Bs[128 * LDSS];
    const int tid = threadIdx.x, bid = blockIdx.x;
    const int nt = bid & 7, mt = bid >> 3;
    f32x4 acc[4][4]; ZERO_ACC(acc);
    gemm_loop(Yb, (long)mt * 128, 1024, 0, WpT, (long)nt * 128, 1024, 0, 32, As, Bs, tid, acc);
    EPI_COORDS
    const int fl = flag[0];
#pragma unroll
    for (int mi = 0; mi < 4; ++mi)
#pragma unroll
        for (int ni = 0; ni < 4; ++ni) {
            long col = nt * 128 + waveN * 64 + ni * 16 + l16;
            float bias = bf2f(cv[4096 + col]);
#pragma unroll
            for (int r = 0; r < 4; ++r) {
                long row = mt * 128 + waveM * 64 + mi * 16 + quad * 4 + r;
                float v = acc[mi][ni][r] + bias;
                if (fl) ((float*)out)[row * 1024 + col] = v;
                else    ((u16*)out)[row * 1024 + col] = f2bf(v);
            }
        }
}

// ---------------- fallback: report ws_size via output constant ----------------
__global__ __launch_bounds__(256) void k_fb(u16* __restrict__ out, long n, float val) {
    long i = (long)blockIdx.x * 256 + threadIdx.x;
    if (i < n) out[i] = f2bf(val);
}

extern "C" void kernel_launch(void* const* d_in, const int* in_sizes, int n_in,
                              void* d_out, int out_size, void* d_ws, size_t ws_size,
                              hipStream_t stream) {
    const void* x     = d_in[0];
    const void* wqkv  = d_in[1];
    const void* bqkv  = d_in[2];
    const void* wgate = d_in[3];
    const void* bgate = d_in[4];
    const void* wproj = d_in[5];
    const void* bproj = d_in[6];
    const void* lng   = d_in[7];
    const void* lnb   = d_in[8];

    const long NEEDED = 178403336L;   // ~170.1 MB
    if (ws_size < (size_t)NEEDED) {   // clean failure that reports ws_size in MB via absmax
        k_fb<<<(int)((out_size + 255) / 256), 256, 0, stream>>>((u16*)d_out, out_size, (float)(ws_size >> 20));
        return;
    }

    char* w = (char*)d_ws;
    u16* XN  = (u16*)(w);                 // 32MB [16384,1024]; dead after gemm1
    u16* ST  = XN;                        // 32MB [16][1024][1024] (alias, written by pass1)
    u16* Q   = (u16*)(w + 33554432L);     // 32MB [16384,1024] (elu(q)+1)
    u16* K   = (u16*)(w + 67108864L);     // 32MB [16384,1024] (k_raw -> k_act); dead after pass2a
    u16* Yb  = K;                         // 32MB y output (alias, written by pass2b)
    u16* G   = (u16*)(w + 100663296L);    // 32MB gate; dead after act
    u16* kT  = G;                         // 32MB [4][1024][4096] (alias); dead after pass1
    u16* P   = G;                         // 32MB [16384,1024] (alias, written by pass2a)
    u16* vT  = (u16*)(w + 134217728L);    // 32MB [4][1024][4096] (written by gemm1 epilogue)
    u16* Wt  = (u16*)(w + 167772160L);    // 8MB  [4096,1024]
    u16* WpT = (u16*)(w + 176160768L);    // 2MB  [1024,1024]
    float* csum = (float*)(w + 178257920L);  // 64KB [16][1024]
    float* den  = (float*)(w + 178323456L);  // 64KB [16384]
    u16* cv     = (u16*)(w + 178388992L);    // 14KB [bqkv|bgate|bproj|lng|lnb]
    int* flag   = (int*)(w + 178403328L);    // 4B  input-dtype flag (1 = f32)

    k_detect<<<1,     256, 0, stream>>>((const u16*)wqkv, flag);
    k_cvec  <<<28,    256, 0, stream>>>(bqkv, bgate, bproj, lng, lnb, flag, cv);
    k_transw<<<20480, 256, 0, stream>>>(wqkv, wgate, wproj, flag, Wt, WpT);
    k_ln    <<<16384, 256, 0, stream>>>(x, cv, flag, XN);
    k_gemm1 <<<4096,  256, 0, stream>>>(XN, Wt, cv, Q, K, G, vT);
    k_act   <<<16384, 256, 0, stream>>>(K, G);
    k_transk<<<4096,  256, 0, stream>>>(K, kT);
    k_csum  <<<64,    256, 0, stream>>>(K, csum);
    k_pass1 <<<1024,  256, 0, stream>>>(kT, vT, ST);
    k_stpre <<<16384, 256, 0, stream>>>(ST);
    k_pass2a<<<1024,  256, 0, stream>>>(Q, K, P);
    k_den   <<<16384, 256, 0, stream>>>(Q, P, csum, den);
    k_pass2b<<<1024,  256, 0, stream>>>(Q, ST, P, vT, den, Yb);
    k_proj  <<<1024,  256, 0, stream>>>(Yb, WpT, cv, flag, d_out);
}

// Round 4
// 739.696 us; speedup vs baseline: 2.2608x; 2.2608x over previous
//
#include <hip/hip_runtime.h>
#include <math.h>

typedef unsigned short u16;
typedef __attribute__((ext_vector_type(8))) short bf16x8;
typedef __attribute__((ext_vector_type(4))) float f32x4;
typedef const __attribute__((address_space(1))) unsigned int* gas_t;
typedef __attribute__((address_space(3))) unsigned int* las_t;

#define BK 32

__device__ __forceinline__ float bf2f(u16 u) {
    unsigned x = ((unsigned)u) << 16; float f; __builtin_memcpy(&f, &x, 4); return f;
}
__device__ __forceinline__ u16 f2bf(float f) {
    unsigned x; __builtin_memcpy(&x, &f, 4);
    unsigned lsb = (x >> 16) & 1u; x += 0x7fffu + lsb; return (u16)(x >> 16);
}

// ---------------- input dtype detector (1 = f32 inputs) ----------------
__global__ __launch_bounds__(256) void k_detect(const u16* __restrict__ wq, int* __restrict__ flag) {
    const int tid = threadIdx.x;
    int cnt = 0;
    for (int i = tid; i < 2048; i += 256) {
        float v = fabsf(bf2f(wq[2 * i]));
        if (!(v < 1e4f) || (v != 0.f && v < 1e-30f)) cnt++;
    }
    for (int off = 32; off; off >>= 1) cnt += __shfl_down(cnt, off, 64);
    __shared__ int red[4];
    int lane = tid & 63, w = tid >> 6;
    if (!lane) red[w] = cnt;
    __syncthreads();
    if (!tid) flag[0] = (red[0] + red[1] + red[2] + red[3] > 204) ? 1 : 0;
}

// ---------------- small-vector convert: [bqkv|bgate|bproj|lng|lnb] -> bf16 ----------------
__global__ __launch_bounds__(256) void k_cvec(const void* __restrict__ bqkv, const void* __restrict__ bgate,
                                              const void* __restrict__ bproj, const void* __restrict__ lng,
                                              const void* __restrict__ lnb, const int* __restrict__ flag,
                                              u16* __restrict__ cv) {
    int i = blockIdx.x * 256 + threadIdx.x;   // 0..7167
    const void* src; int off;
    if (i < 3072)      { src = bqkv;  off = i; }
    else if (i < 4096) { src = bgate; off = i - 3072; }
    else if (i < 5120) { src = bproj; off = i - 4096; }
    else if (i < 6144) { src = lng;   off = i - 5120; }
    else               { src = lnb;   off = i - 6144; }
    cv[i] = flag[0] ? f2bf(((const float*)src)[off]) : ((const u16*)src)[off];
}

// ---------------- m97-style async MFMA 128x128-tile K-loop ----------------
// LDS: As[128][32], Bs[128][32] u16 UNPADDED (global_load_lds = wave-uniform base + lane*16B).
// A: rows ar0.., k-contig, stride as_. B: rows br0.., k-contig, stride bs_.
__device__ __forceinline__ void gemm_loop(const u16* __restrict__ Ab, long ar0, long as_, long ka0,
                                          const u16* __restrict__ Bb, long br0, long bs_, long kb0,
                                          int ksteps, u16* As, u16* Bs, int tid, f32x4 acc[4][4]) {
    const int lane = tid & 63;
    const int wave = tid >> 6;
    const int waveM = (tid >> 7) & 1;
    const int waveN = (tid >> 6) & 1;
    const int quad = lane >> 4, l16 = lane & 15;
    const int rs = wave * 16 + (lane >> 2);     // staging row 0..63
    const int cs = (lane & 3) * 8;              // staging col (u16 units)
    const u16* A0 = Ab + (ar0 + rs) * as_ + ka0 + cs;
    const u16* A1 = Ab + (ar0 + 64 + rs) * as_ + ka0 + cs;
    const u16* B0 = Bb + (br0 + rs) * bs_ + kb0 + cs;
    const u16* B1 = Bb + (br0 + 64 + rs) * bs_ + kb0 + cs;
    u16* lA0 = As + wave * 512;          // wave-uniform LDS bases
    u16* lA1 = As + 2048 + wave * 512;
    u16* lB0 = Bs + wave * 512;
    u16* lB1 = Bs + 2048 + wave * 512;
    for (int kt = 0; kt < ksteps; ++kt) {
        const long ko = (long)kt * BK;
        __builtin_amdgcn_global_load_lds((gas_t)(A0 + ko), (las_t)lA0, 16, 0, 0);
        __builtin_amdgcn_global_load_lds((gas_t)(A1 + ko), (las_t)lA1, 16, 0, 0);
        __builtin_amdgcn_global_load_lds((gas_t)(B0 + ko), (las_t)lB0, 16, 0, 0);
        __builtin_amdgcn_global_load_lds((gas_t)(B1 + ko), (las_t)lB1, 16, 0, 0);
        __syncthreads();   // drains vmcnt -> tile resident in LDS
        bf16x8 af[4], bv[4];
#pragma unroll
        for (int mi = 0; mi < 4; ++mi)
            af[mi] = *(const bf16x8*)(As + (waveM * 64 + mi * 16 + l16) * BK + quad * 8);
#pragma unroll
        for (int ni = 0; ni < 4; ++ni)
            bv[ni] = *(const bf16x8*)(Bs + (waveN * 64 + ni * 16 + l16) * BK + quad * 8);
#pragma unroll
        for (int mi = 0; mi < 4; ++mi)
#pragma unroll
            for (int ni = 0; ni < 4; ++ni)
                acc[mi][ni] = __builtin_amdgcn_mfma_f32_16x16x32_bf16(af[mi], bv[ni], acc[mi][ni], 0, 0, 0);
        __syncthreads();   // all ds_reads done before next kstep overwrites
    }
}

#define EPI_COORDS \
    const int lane = tid & 63; const int quad = lane >> 4; const int l16 = lane & 15; \
    const int waveM = (tid >> 7) & 1; const int waveN = (tid >> 6) & 1;

#define ZERO_ACC(acc) \
    _Pragma("unroll") for (int mi = 0; mi < 4; ++mi) \
    _Pragma("unroll") for (int ni = 0; ni < 4; ++ni) acc[mi][ni] = (f32x4){0.f, 0.f, 0.f, 0.f};

// ---------------- tiled weight transpose (coalesced reads) ----------------
__global__ __launch_bounds__(256) void k_transw(const void* __restrict__ wqkv, const void* __restrict__ wgate,
                                                const void* __restrict__ wproj, const int* __restrict__ flag,
                                                u16* __restrict__ Wt, u16* __restrict__ WpT) {
    const int bid = blockIdx.x, tid = threadIdx.x;   // 1280 blocks: 80 n-tiles x 16 k-tiles
    const int ktl = bid & 15, ntile = bid >> 4;
    const int n0 = ntile * 64, k0 = ktl * 64;
    const int fl = flag[0];
    const void* src; int ld, c0;
    if (n0 < 3072)      { src = wqkv;  ld = 3072; c0 = n0; }
    else if (n0 < 4096) { src = wgate; ld = 1024; c0 = n0 - 3072; }
    else                { src = wproj; ld = 1024; c0 = n0 - 4096; }
    __shared__ u16 t[64][66];
#pragma unroll
    for (int i = 0; i < 16; ++i) {
        int idx = tid + i * 256; int r = idx >> 6, c = idx & 63;   // r=k, c=n (local)
        long off = (long)(k0 + r) * ld + c0 + c;
        float v = fl ? ((const float*)src)[off] : bf2f(((const u16*)src)[off]);
        t[r][c] = f2bf(v);
    }
    __syncthreads();
#pragma unroll
    for (int i = 0; i < 16; ++i) {
        int idx = tid + i * 256; int r = idx >> 6, c = idx & 63;   // r=n, c=k (local)
        int n = n0 + r;
        if (n < 4096) Wt[(long)n * 1024 + k0 + c] = t[c][r];
        else          WpT[(long)(n - 4096) * 1024 + k0 + c] = t[c][r];
    }
}

// ---------------- LayerNorm ----------------
__global__ __launch_bounds__(256) void k_ln(const void* __restrict__ xin, const u16* __restrict__ cv,
                                            const int* __restrict__ flag, u16* __restrict__ XN) {
    const long t = blockIdx.x; const int tid = threadIdx.x;
    const int fl = flag[0];
    float v[4], s = 0.f, sq = 0.f;
#pragma unroll
    for (int i = 0; i < 4; ++i) {
        long a = t * 1024 + tid + i * 256;
        v[i] = fl ? ((const float*)xin)[a] : bf2f(((const u16*)xin)[a]);
        s += v[i]; sq += v[i] * v[i];
    }
    for (int off = 32; off; off >>= 1) { s += __shfl_down(s, off, 64); sq += __shfl_down(sq, off, 64); }
    __shared__ float red[8];
    int lane = tid & 63, w = tid >> 6;
    if (!lane) { red[w] = s; red[4 + w] = sq; }
    __syncthreads();
    float S = red[0] + red[1] + red[2] + red[3];
    float SQ = red[4] + red[5] + red[6] + red[7];
    float mu = S * (1.f / 1024.f);
    float var = SQ * (1.f / 1024.f) - mu * mu;
    float rs = rsqrtf(var + 1e-5f);
#pragma unroll
    for (int i = 0; i < 4; ++i) {
        int col = tid + i * 256;
        XN[t * 1024 + col] = f2bf((v[i] - mu) * rs * bf2f(cv[5120 + col]) + bf2f(cv[6144 + col]));
    }
}

// ---------------- GEMM1: [q|k|v|gate] = XN @ Wt^T + bias ; q: elu+1; v: transposed coalesced ----------------
__global__ __launch_bounds__(256) void k_gemm1(const u16* __restrict__ XN, const u16* __restrict__ Wt,
                                               const u16* __restrict__ cv,
                                               u16* __restrict__ Q, u16* __restrict__ K,
                                               u16* __restrict__ G, u16* __restrict__ vT) {
    __shared__ u16 S[8448];           // gemm: As=S[0..4096), Bs=S[4096..8192); epi: [64][132]
    const int tid = threadIdx.x, bid = blockIdx.x;
    const int nt = bid & 31, mt = bid >> 5;
    f32x4 acc[4][4]; ZERO_ACC(acc);
    gemm_loop(XN, (long)mt * 128, 1024, 0, Wt, (long)nt * 128, 1024, 0, 32, S, S + 4096, tid, acc);
    EPI_COORDS
    const int grp = nt >> 3;   // 0=q 1=k 2=v 3=gate (block-uniform)
    if (grp == 2) {            // v: stage [col][132] in LDS, write t-contiguous
        const int b = mt >> 5; const long tb0 = (long)(mt & 31) * 128;
#pragma unroll
        for (int h = 0; h < 2; ++h) {
            if (waveN == h) {
#pragma unroll
                for (int mi = 0; mi < 4; ++mi)
#pragma unroll
                    for (int ni = 0; ni < 4; ++ni) {
                        int col = ni * 16 + l16;
                        float bias = bf2f(cv[nt * 128 + h * 64 + col]);
#pragma unroll
                        for (int r = 0; r < 4; ++r)
                            S[col * 132 + waveM * 64 + mi * 16 + quad * 4 + r] = f2bf(acc[mi][ni][r] + bias);
                    }
            }
            __syncthreads();
#pragma unroll
            for (int i = 0; i < 8; ++i) {
                int ch = tid + i * 256;                 // 2048 chunks of 4 u16
                int col = ch >> 5, t4 = (ch & 31) * 4;
                uint2 val = *(const uint2*)(S + col * 132 + t4);
                long dg = (nt & 7) * 128 + h * 64 + col;
                *(uint2*)(vT + (long)b * 4194304 + dg * 4096 + tb0 + t4) = val;
            }
            __syncthreads();
        }
    } else {
        u16* dst = (grp == 0) ? Q : (grp == 1) ? K : G;
#pragma unroll
        for (int mi = 0; mi < 4; ++mi)
#pragma unroll
            for (int ni = 0; ni < 4; ++ni) {
                int colg = nt * 128 + waveN * 64 + ni * 16 + l16;
                int d = colg & 1023;
                float bias = (grp < 3) ? bf2f(cv[colg]) : bf2f(cv[3072 + d]);
                int row0 = mt * 128 + waveM * 64 + mi * 16 + quad * 4;
#pragma unroll
                for (int r = 0; r < 4; ++r) {
                    float v = acc[mi][ni][r] + bias;
                    if (grp == 0) v = v > 0.f ? v + 1.f : expf(v);   // elu(q)+1 fused, f32
                    dst[(long)(row0 + r) * 1024 + d] = f2bf(v);
                }
            }
    }
}

// ---------------- k = elu(k_raw * sigmoid(gate)) + 1, in place ----------------
__global__ __launch_bounds__(256) void k_act(u16* __restrict__ K, const u16* __restrict__ G) {
    const long t = blockIdx.x; const int tid = threadIdx.x;
#pragma unroll
    for (int i = 0; i < 4; ++i) {
        long a = t * 1024 + tid + i * 256;
        float kk = bf2f(K[a]) / (1.f + expf(-bf2f(G[a])));
        kk = kk > 0.f ? kk + 1.f : expf(kk);
        K[a] = f2bf(kk);
    }
}

// ---------------- tiled transpose: kT[b][d][t] <- K[t][d] ----------------
__global__ __launch_bounds__(256) void k_transk(const u16* __restrict__ K, u16* __restrict__ kT) {
    const int bid = blockIdx.x, tid = threadIdx.x;   // 256 tt x 16 dt
    const int dt = bid & 15, tt = bid >> 4;
    __shared__ u16 tileS[64][65];
#pragma unroll
    for (int i = 0; i < 16; ++i) {
        int idx = tid + i * 256; int r = idx >> 6, cc = idx & 63;
        tileS[r][cc] = K[(long)(tt * 64 + r) * 1024 + dt * 64 + cc];
    }
    __syncthreads();
    long tg = (long)tt * 64; int b = (int)(tg >> 12); long tb = tg & 4095;
#pragma unroll
    for (int i = 0; i < 16; ++i) {
        int idx = tid + i * 256; int r = idx >> 6, cc = idx & 63;
        kT[(long)b * 4194304 + (long)(dt * 64 + r) * 4096 + tb + cc] = tileS[cc][r];
    }
}

// ---------------- per-chunk k sums: csum[b][c][d] ----------------
__global__ __launch_bounds__(256) void k_csum(const u16* __restrict__ K, float* __restrict__ csum) {
    const int bid = blockIdx.x, tid = threadIdx.x;   // 64 blocks
    const int b = bid >> 4, c = (bid >> 2) & 3, dg = bid & 3;
    const int d = dg * 256 + tid;
    const u16* base = K + ((long)b * 4096 + c * 1024) * 1024 + d;
    float s = 0.f;
    for (int t = 0; t < 1024; ++t) s += bf2f(base[(long)t * 1024]);
    csum[((b * 4 + c) << 10) + d] = s;
}

// ---------------- pass1: ST[b][c][d][e] = sum_s v[s,d] k[s,e] ----------------
__global__ __launch_bounds__(256) void k_pass1(const u16* __restrict__ kT, const u16* __restrict__ vT,
                                               u16* __restrict__ ST) {
    __shared__ u16 S[8192];
    const int tid = threadIdx.x, bid = blockIdx.x;
    const int tile = bid & 63, c = (bid >> 6) & 3, b = bid >> 8;
    const int dt = tile >> 3, et = tile & 7;
    f32x4 acc[4][4]; ZERO_ACC(acc);
    gemm_loop(vT + (long)b * 4194304, (long)dt * 128, 4096, (long)c * 1024,
              kT + (long)b * 4194304, (long)et * 128, 4096, (long)c * 1024, 32, S, S + 4096, tid, acc);
    EPI_COORDS
    u16* dst = ST + ((long)(b * 4 + c) << 20);
#pragma unroll
    for (int mi = 0; mi < 4; ++mi)
#pragma unroll
        for (int ni = 0; ni < 4; ++ni)
#pragma unroll
            for (int r = 0; r < 4; ++r) {
                long d = dt * 128 + waveM * 64 + mi * 16 + quad * 4 + r;
                long e = et * 128 + waveN * 64 + ni * 16 + l16;
                dst[d * 1024 + e] = f2bf(acc[mi][ni][r]);
            }
}

// ---------------- in-place exclusive prefix over chunk states ----------------
__global__ __launch_bounds__(256) void k_stpre(u16* __restrict__ ST) {
    const long gid = (long)blockIdx.x * 256 + threadIdx.x;  // 4M
    const int b = (int)(gid >> 20); const long rem = gid & 0xFFFFF;
    float run = 0.f;
    for (int c = 0; c < 4; ++c) {
        long a = (((long)(b * 4 + c)) << 20) + rem;
        float v = bf2f(ST[a]);
        ST[a] = f2bf(run);
        run += v;
    }
}

// ---------------- pass2a: P[t, s_local] = masked q_t . k_s (intra chunk) ----------------
__global__ __launch_bounds__(256) void k_pass2a(const u16* __restrict__ Q, const u16* __restrict__ K,
                                                u16* __restrict__ P) {
    const int tid = threadIdx.x, bid = blockIdx.x;
    const int tile = bid & 63, c = (bid >> 6) & 3, b = bid >> 8;
    const int ti = tile >> 3, si = tile & 7;
    const long trow0 = (long)b * 4096 + c * 1024 + ti * 128;
    if (si > ti) {  // strictly-upper tile: zeros (block-uniform)
#pragma unroll
        for (int i = 0; i < 64; ++i) {
            int idx = tid + i * 256; int rr = idx >> 7, cc = idx & 127;
            P[(trow0 + rr) * 1024 + si * 128 + cc] = 0;
        }
        return;
    }
    __shared__ u16 S[8192];
    const long srow0 = (long)b * 4096 + c * 1024 + si * 128;
    f32x4 acc[4][4]; ZERO_ACC(acc);
    gemm_loop(Q, trow0, 1024, 0, K, srow0, 1024, 0, 32, S, S + 4096, tid, acc);
    EPI_COORDS
#pragma unroll
    for (int mi = 0; mi < 4; ++mi)
#pragma unroll
        for (int ni = 0; ni < 4; ++ni) {
            int slc = si * 128 + waveN * 64 + ni * 16 + l16;
#pragma unroll
            for (int r = 0; r < 4; ++r) {
                int tl = waveM * 64 + mi * 16 + quad * 4 + r;
                float v = (ti * 128 + tl >= slc) ? acc[mi][ni][r] : 0.f;
                P[(trow0 + tl) * 1024 + slc] = f2bf(v);
            }
        }
}

// ---------------- den[t] = q_t . chunk_prefix + rowsum(P) + eps ----------------
__global__ __launch_bounds__(256) void k_den(const u16* __restrict__ Q, const u16* __restrict__ P,
                                             const float* __restrict__ csum, float* __restrict__ den) {
    const long t = blockIdx.x; const int tid = threadIdx.x;
    const int b = (int)(t >> 12), c = (int)((t >> 10) & 3);
    float s = 0.f;
#pragma unroll
    for (int i = 0; i < 4; ++i) {
        int e = tid + i * 256;
        float kp = 0.f;
        for (int cp = 0; cp < c; ++cp) kp += csum[((b * 4 + cp) << 10) + e];
        s += bf2f(Q[t * 1024 + e]) * kp + bf2f(P[t * 1024 + e]);
    }
    for (int off = 32; off; off >>= 1) s += __shfl_down(s, off, 64);
    __shared__ float red[4];
    int lane = tid & 63, w = tid >> 6;
    if (!lane) red[w] = s;
    __syncthreads();
    if (!tid) den[t] = red[0] + red[1] + red[2] + red[3] + 1e-6f;
}

// ---------------- pass2b: y[t,d] = (q@ST_prefix + P@V)/den ----------------
__global__ __launch_bounds__(256) void k_pass2b(const u16* __restrict__ Q, const u16* __restrict__ ST,
                                                const u16* __restrict__ P, const u16* __restrict__ vT,
                                                const float* __restrict__ den, u16* __restrict__ Yb) {
    __shared__ u16 S[8192];
    const int tid = threadIdx.x, bid = blockIdx.x;
    const int tile = bid & 63, c = (bid >> 6) & 3, b = bid >> 8;
    const int ti = tile >> 3, di = tile & 7;
    const long trow0 = (long)b * 4096 + c * 1024 + ti * 128;
    f32x4 acc[4][4]; ZERO_ACC(acc);
    if (c > 0)  // inter-chunk (prefix is zero for c==0)
        gemm_loop(Q, trow0, 1024, 0, ST + ((long)(b * 4 + c) << 20), (long)di * 128, 1024, 0,
                  32, S, S + 4096, tid, acc);
    // intra-chunk: only s-tiles <= ti carry mass (P upper region zeroed)
    gemm_loop(P, trow0, 1024, 0, vT + (long)b * 4194304, (long)di * 128, 4096, (long)c * 1024,
              (ti + 1) * 4, S, S + 4096, tid, acc);
    EPI_COORDS
#pragma unroll
    for (int mi = 0; mi < 4; ++mi)
#pragma unroll
        for (int ni = 0; ni < 4; ++ni) {
            long d = di * 128 + waveN * 64 + ni * 16 + l16;
#pragma unroll
            for (int r = 0; r < 4; ++r) {
                long t = trow0 + waveM * 64 + mi * 16 + quad * 4 + r;
                Yb[t * 1024 + d] = f2bf(acc[mi][ni][r] / den[t]);
            }
        }
}

// ---------------- proj: out = y @ w_proj + b_proj (dtype-aware store) ----------------
__global__ __launch_bounds__(256) void k_proj(const u16* __restrict__ Yb, const u16* __restrict__ WpT,
                                              const u16* __restrict__ cv, const int* __restrict__ flag,
                                              void* __restrict__ out) {
    __shared__ u16 S[8192];
    const int tid = threadIdx.x, bid = blockIdx.x;
    const int nt = bid & 7, mt = bid >> 3;
    f32x4 acc[4][4]; ZERO_ACC(acc);
    gemm_loop(Yb, (long)mt * 128, 1024, 0, WpT, (long)nt * 128, 1024, 0, 32, S, S + 4096, tid, acc);
    EPI_COORDS
    const int fl = flag[0];
#pragma unroll
    for (int mi = 0; mi < 4; ++mi)
#pragma unroll
        for (int ni = 0; ni < 4; ++ni) {
            long col = nt * 128 + waveN * 64 + ni * 16 + l16;
            float bias = bf2f(cv[4096 + col]);
#pragma unroll
            for (int r = 0; r < 4; ++r) {
                long row = mt * 128 + waveM * 64 + mi * 16 + quad * 4 + r;
                float v = acc[mi][ni][r] + bias;
                if (fl) ((float*)out)[row * 1024 + col] = v;
                else    ((u16*)out)[row * 1024 + col] = f2bf(v);
            }
        }
}

// ---------------- fallback: report ws_size via output constant ----------------
__global__ __launch_bounds__(256) void k_fb(u16* __restrict__ out, long n, float val) {
    long i = (long)blockIdx.x * 256 + threadIdx.x;
    if (i < n) out[i] = f2bf(val);
}

extern "C" void kernel_launch(void* const* d_in, const int* in_sizes, int n_in,
                              void* d_out, int out_size, void* d_ws, size_t ws_size,
                              hipStream_t stream) {
    const void* x     = d_in[0];
    const void* wqkv  = d_in[1];
    const void* bqkv  = d_in[2];
    const void* wgate = d_in[3];
    const void* bgate = d_in[4];
    const void* wproj = d_in[5];
    const void* bproj = d_in[6];
    const void* lng   = d_in[7];
    const void* lnb   = d_in[8];

    const long NEEDED = 178403336L;   // ~170.1 MB
    if (ws_size < (size_t)NEEDED) {
        k_fb<<<(int)((out_size + 255) / 256), 256, 0, stream>>>((u16*)d_out, out_size, (float)(ws_size >> 20));
        return;
    }

    char* w = (char*)d_ws;
    u16* XN  = (u16*)(w);                 // 32MB [16384,1024]; dead after gemm1
    u16* ST  = XN;                        // 32MB [16][1024][1024] (alias)
    u16* Q   = (u16*)(w + 33554432L);     // 32MB (elu(q)+1)
    u16* K   = (u16*)(w + 67108864L);     // 32MB; dead after pass2a
    u16* Yb  = K;                         // 32MB (alias)
    u16* G   = (u16*)(w + 100663296L);    // 32MB gate; dead after act
    u16* kT  = G;                         // (alias); dead after pass1
    u16* P   = G;                         // (alias)
    u16* vT  = (u16*)(w + 134217728L);    // 32MB [4][1024][4096]
    u16* Wt  = (u16*)(w + 167772160L);    // 8MB  [4096,1024]
    u16* WpT = (u16*)(w + 176160768L);    // 2MB  [1024,1024]
    float* csum = (float*)(w + 178257920L);  // 64KB [16][1024]
    float* den  = (float*)(w + 178323456L);  // 64KB [16384]
    u16* cv     = (u16*)(w + 178388992L);    // 14KB
    int* flag   = (int*)(w + 178403328L);    // 4B

    k_detect<<<1,     256, 0, stream>>>((const u16*)wqkv, flag);
    k_cvec  <<<28,    256, 0, stream>>>(bqkv, bgate, bproj, lng, lnb, flag, cv);
    k_transw<<<1280,  256, 0, stream>>>(wqkv, wgate, wproj, flag, Wt, WpT);
    k_ln    <<<16384, 256, 0, stream>>>(x, cv, flag, XN);
    k_gemm1 <<<4096,  256, 0, stream>>>(XN, Wt, cv, Q, K, G, vT);
    k_act   <<<16384, 256, 0, stream>>>(K, G);
    k_transk<<<4096,  256, 0, stream>>>(K, kT);
    k_csum  <<<64,    256, 0, stream>>>(K, csum);
    k_pass1 <<<1024,  256, 0, stream>>>(kT, vT, ST);
    k_stpre <<<16384, 256, 0, stream>>>(ST);
    k_pass2a<<<1024,  256, 0, stream>>>(Q, K, P);
    k_den   <<<16384, 256, 0, stream>>>(Q, P, csum, den);
    k_pass2b<<<1024,  256, 0, stream>>>(Q, ST, P, vT, den, Yb);
    k_proj  <<<1024,  256, 0, stream>>>(Yb, WpT, cv, flag, d_out);
}